// Round 9
// baseline (572.381 us; speedup 1.0000x reference)
//
#include <hip/hip_runtime.h>
#include <cstdint>
#include <cstddef>

typedef __attribute__((ext_vector_type(4))) int i32x4;
typedef __bf16 bf16;
typedef __attribute__((ext_vector_type(8))) __bf16 bf16x8;
typedef __attribute__((ext_vector_type(4))) float f32x4;

#define BM 128
#define BN 128
#define BKB 128   // K-bytes per tile (i8) for the 128^2 fallback gemm
#define GROUP_M 16
#define GM256 4   // grouped-m
#define NXCD 8

__device__ __forceinline__ unsigned bf16_rne(float f) {
  unsigned u = __float_as_uint(f);
  unsigned r = 0x7FFFu + ((u >> 16) & 1u);
  return ((u + r) >> 16) & 0xFFFFu;
}
__device__ __forceinline__ unsigned pack2(float a, float b) {
  return bf16_rne(a) | (bf16_rne(b) << 16);
}
__device__ __forceinline__ int pack4i8(int a, int b, int c, int d) {
  return (a & 0xFF) | ((b & 0xFF) << 8) | ((c & 0xFF) << 16) | (d << 24);
}
__device__ __forceinline__ int q_i8(float v) {
  v = fminf(fmaxf(v, -127.0f), 127.0f);
  return __float2int_rn(v);
}

// ---------------- Phase 1 (R7, kept): per-row int8 quantization --------------
__global__ __launch_bounds__(256) void prep_kernel(
    const float* __restrict__ x, char* __restrict__ xq, float* __restrict__ xscale,
    int M,
    const int* __restrict__ q, const float* __restrict__ scale,
    const int* __restrict__ zp, char* __restrict__ wq, float* __restrict__ wscale,
    int K, int G) {
  __shared__ float red[4];
  const int b = blockIdx.x;
  const int tid = threadIdx.x;

  if (b >= M) {
    // W path: one-pass streaming via analytic row bound.
    const int row = b - M;
    const float* srow = scale + (size_t)row * G;
    const int*   zrow = zp + (size_t)row * G;
    const int lane = tid & 63;
    const int g0 = lane & 31;
    const float s0 = srow[g0];
    const float z0 = (float)zrow[g0];
    float bnd = s0 * fmaxf(z0, 15.0f - z0);
#pragma unroll
    for (int off = 16; off >= 1; off >>= 1)
      bnd = fmaxf(bnd, __shfl_xor(bnd, off));
    const float inv = 127.0f / bnd;
    const int4* src = (const int4*)(q + (size_t)row * K);
    int* dst = (int*)(wq + (size_t)row * K);
#pragma unroll
    for (int i = 0; i < 4; ++i) {
      const int j = tid + 256 * i;
      const int g = j >> 5;
      const float fs = srow[g] * inv;
      const float fo = -(float)zrow[g] * srow[g] * inv;
      int4 qv = src[j];
      dst[j] = pack4i8(__float2int_rn(fmaf((float)qv.x, fs, fo)),
                       __float2int_rn(fmaf((float)qv.y, fs, fo)),
                       __float2int_rn(fmaf((float)qv.z, fs, fo)),
                       __float2int_rn(fmaf((float)qv.w, fs, fo)));
    }
    if (tid == 0) wscale[row] = bnd * (1.0f / 127.0f);
    return;
  }

  // x path: 2-pass (true row max).
  float f[16];
  const float4* src = (const float4*)(x + (size_t)b * K);
#pragma unroll
  for (int i = 0; i < 4; ++i) {
    float4 v = src[tid + 256 * i];
    f[4 * i + 0] = v.x; f[4 * i + 1] = v.y;
    f[4 * i + 2] = v.z; f[4 * i + 3] = v.w;
  }

  float m = 0.f;
#pragma unroll
  for (int j = 0; j < 16; ++j) m = fmaxf(m, fabsf(f[j]));
#pragma unroll
  for (int off = 32; off >= 1; off >>= 1) m = fmaxf(m, __shfl_xor(m, off));
  if ((tid & 63) == 0) red[tid >> 6] = m;
  __syncthreads();
  m = fmaxf(fmaxf(red[0], red[1]), fmaxf(red[2], red[3]));

  const float inv = m > 0.f ? 127.0f / m : 0.f;
  int pk[4];
#pragma unroll
  for (int i = 0; i < 4; ++i)
    pk[i] = pack4i8(q_i8(f[4 * i + 0] * inv), q_i8(f[4 * i + 1] * inv),
                    q_i8(f[4 * i + 2] * inv), q_i8(f[4 * i + 3] * inv));

  int* dst_i32 = (int*)(xq + (size_t)b * K);
#pragma unroll
  for (int i = 0; i < 4; ++i) dst_i32[tid + 256 * i] = pk[i];

  if (tid == 0) xscale[b] = m * (1.0f / 127.0f);
}

// ---------------- async global->LDS helper ----------------
typedef __attribute__((address_space(1))) void gas_void;
typedef __attribute__((address_space(3))) void las_void;

__device__ __forceinline__ void load_lds16(const void* g, void* l) {
  __builtin_amdgcn_global_load_lds((gas_void*)g, (las_void*)l, 16, 0, 0);
}

// ========= Phase 2 (R9): 256x128 tile, BK=64, 2 blocks/CU i8 GEMM ============
// R3-R8 ledger: five schedule variants all 240-270us, MfmaUtil 29-33% — the
// binding constraint is NOT the schedule. Diagnosis: 1 block/CU (128KB LDS +
// ~256 effective regs/wave) -> one 8-wave barrier-locked gang; every
// barrier/drain stalls the whole CU with no independent work to fill pipes.
// Perfect-overlap floor is ~2900 cy/tile vs 6100 measured.
// R9: shrink to 256x128 tile, BK=64 bytes (one MFMA K-slice):
//   LDS = 2buf x (256 A-rows + 128 B-rows) x 64B = 48 KB  (2 blocks <= 160K)
//   per-wave output 128x32 -> acc 64 regs; __launch_bounds__(512,4) caps
//   VGPR at 128 -> 16 waves/CU = 2 blocks resident. Cross-block overlap
//   fills barrier stalls; schedule stays simple (stage t+1 -> nxt, read,
//   MFMA, vmcnt(0)+barrier; alternation race-safety as before).
// LDS swizzle for 64B rows: chunk kq in [0,4) of row r at slot
//   r*4 + (kq ^ ((r>>1)&3))  -> 16 lanes hit 8 bank-pair starts x2 = 2-way
//   (free, m136). Staging invariant: row+128 has same swizzle (128%4==0 on
//   the (r>>1)&3 field), so aoff1 = aoff0 + 128*K.

#define STAGE_A2(buf, ktb) do {                                               \
    load_lds16(A + abase + (size_t)(ktb) + aoff0, &Al[buf][tid * 16]);        \
    load_lds16(A + abase + (size_t)(ktb) + aoff1, &Al[buf][(512 + tid) * 16]);\
  } while (0)

#define STAGE_B2(buf, ktb) do {                                               \
    load_lds16(Bw + bbase + (size_t)(ktb) + boff0, &Bl[buf][tid * 16]);       \
  } while (0)

__global__ __launch_bounds__(512, 4) void gemm_i8_256(
    const char* __restrict__ A,        // [M][K] i8
    const char* __restrict__ Bw,       // [N][K] i8
    const float* __restrict__ ascale,  // [M]
    const float* __restrict__ bscale,  // [N]
    const float* __restrict__ bias,    // [N]
    float* __restrict__ C,             // [M][N] fp32
    int M, int N, int K) {
  __shared__ __align__(16) char Al[2][256 * 64];   // 2 x 16 KB
  __shared__ __align__(16) char Bl[2][128 * 64];   // 2 x  8 KB
  const int tid  = threadIdx.x;
  const int wave = tid >> 6;
  const int lane = tid & 63;
  const int quad = lane >> 4;
  const int l16  = lane & 15;
  const int wq3  = wave & 3;
  const int wmb  = (wave >> 2) * 128;  // wave row base (2 M-waves)
  const int wnb  = wq3 * 32;           // wave col base (4 N-waves x 32)

  // XCD-bijective chunked remap (launcher guarantees nblocks % 8 == 0)
  const int nbm = M / 256, nbn = N / 128;
  const int cpx = (nbm * nbn) / NXCD;
  const int swz = ((int)blockIdx.x % NXCD) * cpx + (int)blockIdx.x / NXCD;
  // grouped-m
  const int per_group = GM256 * nbn;
  const int gid = swz / per_group;
  const int rem = swz - gid * per_group;
  int gm = nbm - gid * GM256; if (gm > GM256) gm = GM256;
  const int bm = (gid * GM256 + (rem % gm)) * 256;
  const int bn = (rem / gm) * 128;

  // Staging invariants. Slot s: row = s>>2, lds chunk c = s&3,
  // global chunk kq = c ^ ((row>>1)&3). Thread t owns A slots {t, 512+t}
  // (rows r0, r0+128) and B slot {t} (row r0), r0 = t>>2.
  const int r0 = tid >> 2;
  const int kqg = ((tid & 3) ^ ((r0 >> 1) & 3)) * 16;
  const size_t aoff0 = (size_t)r0 * K + kqg;
  const size_t aoff1 = aoff0 + (size_t)128 * K;
  const size_t boff0 = aoff0;
  const size_t abase = (size_t)bm * K;
  const size_t bbase = (size_t)bn * K;
  const int NT = K / 64;

  i32x4 acc[8][2];
#pragma unroll
  for (int i = 0; i < 8; ++i)
#pragma unroll
    for (int j = 0; j < 2; ++j)
      acc[i][j] = (i32x4){0, 0, 0, 0};

  // Prologue: stage tile0 -> buf0, drain, barrier.
  STAGE_A2(0, 0);
  STAGE_B2(0, 0);
  asm volatile("s_waitcnt vmcnt(0)" ::: "memory");
  __builtin_amdgcn_s_barrier();
  __builtin_amdgcn_sched_barrier(0);

  for (int t = 0; t < NT; ++t) {
    const int cur = t & 1;
    const int nxt = cur ^ 1;
    const int kt1 = (t + 1) * 64;

    if (t + 1 < NT) {
      STAGE_A2(nxt, kt1);
      STAGE_B2(nxt, kt1);
    }

    // B fragments (2 x b128), then per-A-fragment: 1 ds_read + 2 MFMAs.
    // Keeps live regs low (acc 64 + bfr 8 + ~1-3 afr); compiler pipelines
    // with counted lgkmcnt under the 128-VGPR cap.
    i32x4 bfr[2];
#pragma unroll
    for (int j = 0; j < 2; ++j) {
      int n = wnb + j * 16 + l16;
      bfr[j] = *(const i32x4*)&Bl[cur][(n * 4 + (quad ^ ((n >> 1) & 3))) * 16];
    }
    __builtin_amdgcn_s_setprio(1);
#pragma unroll
    for (int tm = 0; tm < 8; ++tm) {
      int row = wmb + tm * 16 + l16;
      i32x4 afr =
          *(const i32x4*)&Al[cur][(row * 4 + (quad ^ ((row >> 1) & 3))) * 16];
#pragma unroll
      for (int j = 0; j < 2; ++j)
        acc[tm][j] = __builtin_amdgcn_mfma_i32_16x16x64_i8(
            afr, bfr[j], acc[tm][j], 0, 0, 0);
    }
    __builtin_amdgcn_s_setprio(0);

    asm volatile("s_waitcnt vmcnt(0)" ::: "memory");
    __builtin_amdgcn_s_barrier();
    __builtin_amdgcn_sched_barrier(0);
  }

  // Epilogue: D row = quad*4 + v, col = lane&15 (shape-determined).
#pragma unroll
  for (int tn = 0; tn < 2; ++tn) {
    int col = bn + wnb + tn * 16 + l16;
    float bv = bias[col];
    float ws = bscale[col];
#pragma unroll
    for (int tm = 0; tm < 8; ++tm) {
      int row0 = bm + wmb + tm * 16 + quad * 4;
#pragma unroll
      for (int v = 0; v < 4; ++v) {
        float val = ascale[row0 + v] * ws * (float)acc[tm][tn][v] + bv;
        __builtin_nontemporal_store(val, &C[(size_t)(row0 + v) * N + col]);
      }
    }
  }
}

// ---------------- Fallback A: 128^2 i8 GEMM (known-good) ---------------------
__global__ __launch_bounds__(256) void gemm_i8_kernel(
    const char* __restrict__ A, const char* __restrict__ Bw,
    const float* __restrict__ ascale, const float* __restrict__ bscale,
    const float* __restrict__ bias, float* __restrict__ C,
    int M, int N, int K) {
  __shared__ __align__(16) char Alds[BM * BKB];
  __shared__ __align__(16) char Blds[BN * BKB];
  const int tid  = threadIdx.x;
  const int wave = tid >> 6;
  const int lane = tid & 63;
  const int quad = lane >> 4;
  const int l16  = lane & 15;

  const int nbm = M / BM;
  const int nbn = N / BN;
  int flat = blockIdx.x;
  int per_group = GROUP_M * nbn;
  int gid = flat / per_group;
  int rem = flat - gid * per_group;
  int gm = nbm - gid * GROUP_M;
  if (gm > GROUP_M) gm = GROUP_M;
  const int bm = (gid * GROUP_M + (rem % gm)) * BM;
  const int bn = (rem / gm) * BN;

  const int wm = (wave & 1) * 64;
  const int wn = (wave >> 1) * 64;

  i32x4 acc[4][4];
#pragma unroll
  for (int i = 0; i < 4; ++i)
#pragma unroll
    for (int j = 0; j < 4; ++j)
      acc[i][j] = (i32x4){0, 0, 0, 0};

  for (int kt = 0; kt < K; kt += BKB) {
#pragma unroll
    for (int t = 0; t < 4; ++t) {
      int s0 = (wave * 4 + t) * 64;
      int s  = s0 + lane;
      int m  = s >> 3;
      int kq = (s & 7) ^ (m & 7);
      load_lds16(A  + (size_t)(bm + m) * K + kt + kq * 16, &Alds[s0 * 16]);
      load_lds16(Bw + (size_t)(bn + m) * K + kt + kq * 16, &Blds[s0 * 16]);
    }
    __syncthreads();

#pragma unroll
    for (int ks = 0; ks < 2; ++ks) {
      i32x4 af[4], bfr[4];
#pragma unroll
      for (int tm = 0; tm < 4; ++tm) {
        int m  = wm + tm * 16 + l16;
        int kq = ks * 4 + quad;
        af[tm] = *(const i32x4*)&Alds[(m * 8 + (kq ^ (m & 7))) * 16];
      }
#pragma unroll
      for (int tn = 0; tn < 4; ++tn) {
        int n  = wn + tn * 16 + l16;
        int kq = ks * 4 + quad;
        bfr[tn] = *(const i32x4*)&Blds[(n * 8 + (kq ^ (n & 7))) * 16];
      }
#pragma unroll
      for (int tm = 0; tm < 4; ++tm)
#pragma unroll
        for (int tn = 0; tn < 4; ++tn)
          acc[tm][tn] = __builtin_amdgcn_mfma_i32_16x16x64_i8(
              af[tm], bfr[tn], acc[tm][tn], 0, 0, 0);
    }
    __syncthreads();
  }

#pragma unroll
  for (int tn = 0; tn < 4; ++tn) {
    int col = bn + wn + tn * 16 + l16;
    float bv = bias[col];
    float ws = bscale[col];
#pragma unroll
    for (int tm = 0; tm < 4; ++tm) {
      int row0 = bm + wm + tm * 16 + quad * 4;
#pragma unroll
      for (int v = 0; v < 4; ++v) {
        float val = ascale[row0 + v] * ws * (float)acc[tm][tn][v] + bv;
        __builtin_nontemporal_store(val, &C[(size_t)(row0 + v) * N + col]);
      }
    }
  }
}

// ---------------- Fallback B: fused bf16 dequant GEMM (known-correct) --------
__global__ __launch_bounds__(256) void gemm_fused_kernel(
    const float* __restrict__ X, const int* __restrict__ Q,
    const float* __restrict__ scale, const int* __restrict__ zp,
    const float* __restrict__ bias, float* __restrict__ C,
    int M, int N, int K, int G) {
  __shared__ __align__(16) bf16 Alds[128 * 64];
  __shared__ __align__(16) bf16 Blds[128 * 64];
  const int tid  = threadIdx.x;
  const int wave = tid >> 6;
  const int lane = tid & 63;
  const int quad = lane >> 4;
  const int l16  = lane & 15;
  const int bm = blockIdx.y * 128;
  const int bn = blockIdx.x * 128;
  const int wm = (wave & 1) * 64;
  const int wn = (wave >> 1) * 64;

  f32x4 acc[4][4];
#pragma unroll
  for (int i = 0; i < 4; ++i)
#pragma unroll
    for (int j = 0; j < 4; ++j)
      acc[i][j] = (f32x4){0.f, 0.f, 0.f, 0.f};

  for (int kt = 0; kt < K; kt += 64) {
#pragma unroll
    for (int i = 0; i < 4; ++i) {
      int c = tid + i * 256;
      int m = c >> 3;
      int kq = (c & 7) ^ (m & 7);
      const float* src = X + (size_t)(bm + m) * K + kt + kq * 8;
      float4 v0 = *(const float4*)src;
      float4 v1 = *(const float4*)(src + 4);
      uint4 p;
      p.x = pack2(v0.x, v0.y); p.y = pack2(v0.z, v0.w);
      p.z = pack2(v1.x, v1.y); p.w = pack2(v1.z, v1.w);
      *(uint4*)&Alds[c * 8] = p;
    }
#pragma unroll
    for (int i = 0; i < 4; ++i) {
      int c = tid + i * 256;
      int n = c >> 3;
      int kq = (c & 7) ^ (n & 7);
      int kcol = kt + kq * 8;
      size_t row = (size_t)(bn + n);
      int g = kcol >> 7;
      float s = scale[row * G + g];
      float z = (float)zp[row * G + g];
      const int* src = Q + row * K + kcol;
      int4 q0 = *(const int4*)src;
      int4 q1 = *(const int4*)(src + 4);
      uint4 p;
      p.x = pack2(((float)q0.x - z) * s, ((float)q0.y - z) * s);
      p.y = pack2(((float)q0.z - z) * s, ((float)q0.w - z) * s);
      p.z = pack2(((float)q1.x - z) * s, ((float)q1.y - z) * s);
      p.w = pack2(((float)q1.z - z) * s, ((float)q1.w - z) * s);
      *(uint4*)&Blds[c * 8] = p;
    }
    __syncthreads();

#pragma unroll
    for (int ks = 0; ks < 2; ++ks) {
      bf16x8 af[4], bfr[4];
#pragma unroll
      for (int tm = 0; tm < 4; ++tm) {
        int m  = wm + tm * 16 + l16;
        int kq = ks * 4 + quad;
        af[tm] = *(const bf16x8*)&Alds[(m * 8 + (kq ^ (m & 7))) * 8];
      }
#pragma unroll
      for (int tn = 0; tn < 4; ++tn) {
        int n  = wn + tn * 16 + l16;
        int kq = ks * 4 + quad;
        bfr[tn] = *(const bf16x8*)&Blds[(n * 8 + (kq ^ (n & 7))) * 8];
      }
#pragma unroll
      for (int tm = 0; tm < 4; ++tm)
#pragma unroll
        for (int tn = 0; tn < 4; ++tn)
          acc[tm][tn] = __builtin_amdgcn_mfma_f32_16x16x32_bf16(
              af[tm], bfr[tn], acc[tm][tn], 0, 0, 0);
    }
    __syncthreads();
  }

#pragma unroll
  for (int tn = 0; tn < 4; ++tn) {
    int col = bn + wn + tn * 16 + l16;
    float bv = bias[col];
#pragma unroll
    for (int tm = 0; tm < 4; ++tm) {
      int row0 = bm + wm + tm * 16 + quad * 4;
#pragma unroll
      for (int v = 0; v < 4; ++v)
        C[(size_t)(row0 + v) * N + col] = acc[tm][tn][v] + bv;
    }
  }
}

extern "C" void kernel_launch(void* const* d_in, const int* in_sizes, int n_in,
                              void* d_out, int out_size, void* d_ws, size_t ws_size,
                              hipStream_t stream) {
  const float* x     = (const float*)d_in[0];
  const int*   qw    = (const int*)d_in[1];
  const float* scale = (const float*)d_in[2];
  const int*   zp    = (const int*)d_in[3];
  const float* bias  = (const float*)d_in[4];
  float* out = (float*)d_out;

  const int O = in_sizes[4];                 // 11008
  const int I = (int)(in_sizes[1] / O);      // 4096
  const int M = (int)(in_sizes[0] / I);      // 4096 (= B*S)
  const int G = in_sizes[2] / O;             // 32
  const int K = I, N = O;

  // ws layout: xq[M*K] i8 | xscale[M] f32 | wq[N*K] i8 | wscale[N] f32
  size_t off_xq = 0;
  size_t off_xs = off_xq + (size_t)M * K;
  size_t off_wq = (off_xs + (size_t)M * 4 + 255) & ~(size_t)255;
  size_t off_ws_ = off_wq + (size_t)N * K;
  size_t need   = ((off_ws_ + (size_t)N * 4 + 255) & ~(size_t)255);

  if (ws_size >= need && K == 4096) {
    char*  xq = (char*)d_ws + off_xq;
    float* xs = (float*)((char*)d_ws + off_xs);
    char*  wq = (char*)d_ws + off_wq;
    float* wsc = (float*)((char*)d_ws + off_ws_);

    prep_kernel<<<M + N, 256, 0, stream>>>(x, xq, xs, M, qw, scale, zp, wq, wsc, K, G);

    const int nb = (M / 256) * (N / 128);
    if ((M % 256) == 0 && (N % 128) == 0 && (nb % NXCD) == 0 && (K % 64) == 0) {
      gemm_i8_256<<<nb, 512, 0, stream>>>(xq, wq, xs, wsc, bias, out, M, N, K);
    } else {
      int nblocks = (M / BM) * (N / BN);
      gemm_i8_kernel<<<nblocks, 256, 0, stream>>>(xq, wq, xs, wsc, bias, out, M, N, K);
    }
  } else {
    dim3 gemm_grid((unsigned)(N / 128), (unsigned)(M / 128));
    gemm_fused_kernel<<<gemm_grid, 256, 0, stream>>>(x, qw, scale, zp, bias, out,
                                                     M, N, K, G);
  }
}